// Round 11
// baseline (723.650 us; speedup 1.0000x reference)
//
#include <hip/hip_runtime.h>
#include <hip/hip_fp16.h>

typedef unsigned short u16;
typedef unsigned int u32;

#define B_   256
#define T_   512
#define OBS_ 256
#define H_   128
#define G4_  512   // 4*H
#define LAT_ 16

typedef _Float16 half8_t __attribute__((ext_vector_type(8)));
typedef _Float16 half2_t __attribute__((ext_vector_type(2)));
typedef float    f32x4_t __attribute__((ext_vector_type(4)));

__device__ __forceinline__ u16 f2h(float x) { return __half_as_ushort(__float2half(x)); }
__device__ __forceinline__ float h2f(u16 u) { return __half2float(__ushort_as_half(u)); }
__device__ __forceinline__ float frcp(float x) { return __builtin_amdgcn_rcpf(x); }
__device__ __forceinline__ float fsigmoid(float x) { return frcp(1.f + __expf(-x)); }
__device__ __forceinline__ float ftanh(float x) { return 1.f - 2.f * frcp(1.f + __expf(2.f * x)); }

// ---------------------------------------------------------------------------
// Column permutations (baked into prep):
//  sigma(s): Xw/bias storage col s = w*64 + kg*16 + ti*4 + q  ->  original col
//            q*128 + (w*16 + ti*4 + kg).   (thread (w,kg) reads 16 contiguous
//            u16 per step covering its 4 tiles x 4 gates)
//  perm_g(g): WhA storage row g -> original gate col (g&3)*128 + (g>>2).
//            (D row g = tile*16 + kg*4 + r  ->  gate type r of h-col tile*4+kg)
// ---------------------------------------------------------------------------
__device__ __forceinline__ int sigma_c(int s) {
  return (s & 3) * 128 + (s >> 6) * 16 + ((s >> 2) & 3) * 4 + ((s >> 4) & 3);
}
__device__ __forceinline__ int perm_g(int g) { return (g & 3) * 128 + (g >> 2); }

// ---------------------------------------------------------------------------
// prep: Wxt[s][k]  = f16(Wx[k][sigma(s)])                     (512 x 256)
//       WhA[g][k2] = pack(f16(Wh[2k2][perm_g(g)]), f16(Wh[2k2+1][perm_g(g)]))
//       biasp[s]   = bias[sigma(s)]
// ---------------------------------------------------------------------------
__global__ __launch_bounds__(256) void prep_kernel(const float* __restrict__ Wx,
                                                   const float* __restrict__ Wh,
                                                   const float* __restrict__ bias,
                                                   u16* __restrict__ Wxt,
                                                   u32* __restrict__ WhA,
                                                   float* __restrict__ biasp) {
  int idx = blockIdx.x * 256 + threadIdx.x;
  if (idx < G4_ * OBS_) {
    int s = idx / OBS_, k = idx % OBS_;
    Wxt[idx] = f2h(Wx[(size_t)k * G4_ + sigma_c(s)]);
  } else if (idx < G4_ * OBS_ + 64 * G4_) {
    int i2 = idx - G4_ * OBS_;
    int g = i2 >> 6, k2 = i2 & 63;
    int pg = perm_g(g);
    u32 lo = f2h(Wh[(size_t)(2 * k2) * G4_ + pg]);
    u32 hi = f2h(Wh[(size_t)(2 * k2 + 1) * G4_ + pg]);
    WhA[(size_t)g * 64 + k2] = lo | (hi << 16);
  } else if (idx < G4_ * OBS_ + 64 * G4_ + G4_) {
    int s = idx - G4_ * OBS_ - 64 * G4_;
    biasp[s] = bias[sigma_c(s)];
  }
}

// ---------------------------------------------------------------------------
// gemm_xw: Xw[m][s] = f16( sum_k xs_row(m)[k] * Wxt[s][k] + biasp[s] ).
// 128x128 tile, BK=64, 4 waves, 4x4 frags; C-init = bias (new in R10).
// ---------------------------------------------------------------------------
__global__ __launch_bounds__(256, 2) void gemm_xw(const float* __restrict__ xs,
                                                  const u16* __restrict__ Wxt,
                                                  const float* __restrict__ biasp,
                                                  u16* __restrict__ Xw,
                                                  int t0, int ct_log2) {
  __shared__ __align__(16) u16 As[128][88];
  __shared__ __align__(16) u16 Bs[128][88];

  const int tid  = threadIdx.x;
  const int lane = tid & 63;
  const int w    = tid >> 6;
  const int qr   = (w & 1) * 64;
  const int qc   = (w >> 1) * 64;
  const int bn   = blockIdx.x;
  const int bm   = blockIdx.y;

  f32x4_t acc[4][4];
#pragma unroll
  for (int ni = 0; ni < 4; ++ni) {
    float b = biasp[bn * 128 + qc + ni * 16 + (lane & 15)];
#pragma unroll
    for (int mi = 0; mi < 4; ++mi)
      acc[mi][ni] = (f32x4_t){b, b, b, b};
  }

  const int row  = tid >> 1;
  const int half = (tid & 1) * 32;
  const int m    = bm * 128 + row;
  const int bb   = m >> ct_log2;
  const int tau  = m & ((1 << ct_log2) - 1);
  const float* asrc = xs + (size_t)(bb * T_ + t0 + tau) * OBS_ + half;
  const u16*   bsrc = Wxt + (size_t)(bn * 128 + row) * OBS_ + half;

  for (int k0 = 0; k0 < OBS_; k0 += 64) {
    {
      const float* sp = asrc + k0;
#pragma unroll
      for (int i = 0; i < 4; ++i) {
        float4 v0 = *(const float4*)(sp + i * 8);
        float4 v1 = *(const float4*)(sp + i * 8 + 4);
        uint4 pk;
        pk.x = (u32)f2h(v0.x) | ((u32)f2h(v0.y) << 16);
        pk.y = (u32)f2h(v0.z) | ((u32)f2h(v0.w) << 16);
        pk.z = (u32)f2h(v1.x) | ((u32)f2h(v1.y) << 16);
        pk.w = (u32)f2h(v1.z) | ((u32)f2h(v1.w) << 16);
        *(uint4*)&As[row][half + i * 8] = pk;
      }
    }
    {
      const u16* sp = bsrc + k0;
#pragma unroll
      for (int i = 0; i < 4; ++i)
        *(uint4*)&Bs[row][half + i * 8] = *(const uint4*)(sp + i * 8);
    }
    __syncthreads();
#pragma unroll
    for (int ks = 0; ks < 2; ++ks) {
      const int kc = ks * 32 + (lane >> 4) * 8;
      half8_t af[4], bf[4];
#pragma unroll
      for (int mi = 0; mi < 4; ++mi) af[mi] = *(const half8_t*)&As[qr + mi * 16 + (lane & 15)][kc];
#pragma unroll
      for (int ni = 0; ni < 4; ++ni) bf[ni] = *(const half8_t*)&Bs[qc + ni * 16 + (lane & 15)][kc];
#pragma unroll
      for (int mi = 0; mi < 4; ++mi)
#pragma unroll
        for (int ni = 0; ni < 4; ++ni)
          acc[mi][ni] = __builtin_amdgcn_mfma_f32_16x16x32_f16(af[mi], bf[ni], acc[mi][ni], 0, 0, 0);
    }
    __syncthreads();
  }
#pragma unroll
  for (int mi = 0; mi < 4; ++mi)
#pragma unroll
    for (int ni = 0; ni < 4; ++ni)
#pragma unroll
      for (int r = 0; r < 4; ++r) {
        int mm = bm * 128 + qr + mi * 16 + (lane >> 4) * 4 + r;
        int nn = bn * 128 + qc + ni * 16 + (lane & 15);
        Xw[(size_t)mm * G4_ + nn] = f2h(acc[mi][ni][r]);
      }
}

// ---------------------------------------------------------------------------
// lstm_mfma (R10): 16 blocks x 512 threads; block = 16 batch rows; recurrence
// dots on the matrix pipe.  Per step: 32 tiles x 4 K-frags of 16x16x32 MFMA.
// A = Wh, loaded ONCE via asm then vmcnt(0) IMMEDIATELY (spill-safe after).
// B = h from LDS [row][k2] stride-72 (4 x ds_read_b128 per thread per step).
// Xw: NORMAL loads (compiler waitcnt = correct by construction), 4-slot
// rotation, reload-after-consume (3-step lead).  No counted vmcnt anywhere.
// ---------------------------------------------------------------------------
#define HLS2 72   // u32 stride per batch row (16B-aligned, banks spread)

__global__ __launch_bounds__(512, 2)
void lstm_mfma(const u16* __restrict__ Xw,
               const u32* __restrict__ WhA,
               float* __restrict__ c_ws,
               u16* __restrict__ h_ws,
               int t0, int CT) {
  const int tid  = threadIdx.x;
  const int lane = tid & 63;
  const int wave = tid >> 6;      // 0..7
  const int n    = lane & 15;     // batch row within the 16-row group
  const int kg   = lane >> 4;     // 0..3 (k-slice / j-subindex)
  const int b0   = blockIdx.x * 16;

  __shared__ u32 hl[2][16 * HLS2];

  // ---- A-fragments (Wh): asm loads, then settle IMMEDIATELY ----
  uint4 A[4][4];
#pragma unroll
  for (int ti = 0; ti < 4; ++ti) {
    const int mg = (wave * 4 + ti) * 16 + n;
    const u32* ap = WhA + (size_t)mg * 64 + kg * 4;
#pragma unroll
    for (int kf = 0; kf < 4; ++kf)
      asm volatile("global_load_dwordx4 %0, %1, off" : "=v"(A[ti][kf]) : "v"(ap + kf * 16));
  }
  asm volatile("s_waitcnt vmcnt(0)" ::: "memory");
  __builtin_amdgcn_sched_barrier(0);

  // ---- state init ----
  float c_reg[4], h_last[4];
#pragma unroll
  for (int ti = 0; ti < 4; ++ti) { c_reg[ti] = 0.f; h_last[ti] = 0.f; }
  if (t0 != 0) {
#pragma unroll
    for (int ti = 0; ti < 4; ++ti)
      c_reg[ti] = c_ws[(size_t)(b0 + n) * 128 + (wave * 4 + ti) * 4 + kg];
  }
  {
    const u32* hws32 = (const u32*)h_ws;
    for (int idx = tid; idx < 16 * 64; idx += 512) {
      int r = idx >> 6, k2 = idx & 63;
      hl[0][r * HLS2 + k2] = (t0 == 0) ? 0u : hws32[(size_t)(b0 + r) * 64 + k2];
    }
  }
  __syncthreads();

  // ---- Xw base: this thread's 16 contiguous u16 per step ----
  const u16* xrow = Xw + (size_t)((b0 + n) * CT) * 512 + wave * 64 + kg * 16;

  auto step = [&](const uint4& va, const uint4& vb, int cur) {
    const u32* hb = hl[cur];
    uint4 Bf[4];
#pragma unroll
    for (int kf = 0; kf < 4; ++kf)
      Bf[kf] = *(const uint4*)&hb[n * HLS2 + kf * 16 + kg * 4];
    u32 xv[8] = {va.x, va.y, va.z, va.w, vb.x, vb.y, vb.z, vb.w};
#pragma unroll
    for (int ti = 0; ti < 4; ++ti) {
      f32x4_t acc = (f32x4_t){0.f, 0.f, 0.f, 0.f};
#pragma unroll
      for (int kf = 0; kf < 4; ++kf)
        acc = __builtin_amdgcn_mfma_f32_16x16x32_f16(
            __builtin_bit_cast(half8_t, A[ti][kf]),
            __builtin_bit_cast(half8_t, Bf[kf]), acc, 0, 0, 0);
      half2_t xlo = __builtin_bit_cast(half2_t, xv[2 * ti]);
      half2_t xhi = __builtin_bit_cast(half2_t, xv[2 * ti + 1]);
      float ig = fsigmoid(acc[0] + (float)xlo[0]);
      float fg = fsigmoid(acc[1] + (float)xlo[1]);
      float gt = ftanh   (acc[2] + (float)xhi[0]);
      float og = fsigmoid(acc[3] + (float)xhi[1]);
      c_reg[ti] = fmaf(fg, c_reg[ti], ig * gt);
      float h = og * ftanh(c_reg[ti]);
      h_last[ti] = h;
      const int j = (wave * 4 + ti) * 4 + kg;
      ((u16*)&hl[cur ^ 1][0])[(n * HLS2 + (j >> 1)) * 2 + (j & 1)] = f2h(h);
    }
    __syncthreads();
  };

  // ---- prologue: load xw for t = 0..3 (normal loads) ----
  uint4 q0a = *(const uint4*)(xrow + 0 * 512);
  uint4 q0b = *(const uint4*)(xrow + 0 * 512 + 8);
  uint4 q1a = *(const uint4*)(xrow + 1 * 512);
  uint4 q1b = *(const uint4*)(xrow + 1 * 512 + 8);
  uint4 q2a = *(const uint4*)(xrow + 2 * 512);
  uint4 q2b = *(const uint4*)(xrow + 2 * 512 + 8);
  uint4 q3a = *(const uint4*)(xrow + 3 * 512);
  uint4 q3b = *(const uint4*)(xrow + 3 * 512 + 8);

  for (int base = 0; base < CT; base += 4) {
    int r0 = base + 4 < CT ? base + 4 : CT - 1;   // tail reloads are dead
    int r1 = base + 5 < CT ? base + 5 : CT - 1;
    int r2 = base + 6 < CT ? base + 6 : CT - 1;
    int r3 = base + 7 < CT ? base + 7 : CT - 1;
    step(q0a, q0b, 0);
    q0a = *(const uint4*)(xrow + (size_t)r0 * 512);
    q0b = *(const uint4*)(xrow + (size_t)r0 * 512 + 8);
    step(q1a, q1b, 1);
    q1a = *(const uint4*)(xrow + (size_t)r1 * 512);
    q1b = *(const uint4*)(xrow + (size_t)r1 * 512 + 8);
    step(q2a, q2b, 0);
    q2a = *(const uint4*)(xrow + (size_t)r2 * 512);
    q2b = *(const uint4*)(xrow + (size_t)r2 * 512 + 8);
    step(q3a, q3b, 1);
    q3a = *(const uint4*)(xrow + (size_t)r3 * 512);
    q3b = *(const uint4*)(xrow + (size_t)r3 * 512 + 8);
  }

#pragma unroll
  for (int ti = 0; ti < 4; ++ti) {
    const int j = (wave * 4 + ti) * 4 + kg;
    c_ws[(size_t)(b0 + n) * 128 + j] = c_reg[ti];
    h_ws[(size_t)(b0 + n) * 128 + j] = f2h(h_last[ti]);
  }
}

// ---------------------------------------------------------------------------
// head: out1 = relu(h @ W1 + b1); p = out1 @ W2 + b2; split mean/logvar.
// ---------------------------------------------------------------------------
__global__ __launch_bounds__(128) void head_kernel(const u16* __restrict__ h_ws,
                                                   const float* __restrict__ W1,
                                                   const float* __restrict__ b1,
                                                   const float* __restrict__ W2,
                                                   const float* __restrict__ b2,
                                                   float* __restrict__ out) {
  const int bb = blockIdx.x;
  const int j  = threadIdx.x;
  __shared__ float hs[128];
  __shared__ float o1[128];
  hs[j] = h2f(h_ws[bb * 128 + j]);
  __syncthreads();
  float acc = b1[j];
#pragma unroll 8
  for (int k = 0; k < 128; ++k) acc = fmaf(hs[k], W1[(size_t)k * 128 + j], acc);
  o1[j] = fmaxf(acc, 0.f);
  __syncthreads();
  if (j < 2 * LAT_) {
    float acc2 = b2[j];
#pragma unroll 8
    for (int k = 0; k < 128; ++k) acc2 = fmaf(o1[k], W2[(size_t)k * (2 * LAT_) + j], acc2);
    if (j < LAT_) out[(size_t)bb * LAT_ + j] = acc2;                       // mean
    else          out[(size_t)B_ * LAT_ + (size_t)bb * LAT_ + (j - LAT_)] = acc2;  // logvar
  }
}

// ---------------------------------------------------------------------------
extern "C" void kernel_launch(void* const* d_in, const int* in_sizes, int n_in,
                              void* d_out, int out_size, void* d_ws, size_t ws_size,
                              hipStream_t stream) {
  const float* xs   = (const float*)d_in[0];
  const float* Wx   = (const float*)d_in[1];
  const float* Wh   = (const float*)d_in[2];
  const float* bias = (const float*)d_in[3];
  const float* W1   = (const float*)d_in[4];
  const float* b1   = (const float*)d_in[5];
  const float* W2   = (const float*)d_in[6];
  const float* b2   = (const float*)d_in[7];
  float* out = (float*)d_out;

  char* ws = (char*)d_ws;
  u16* Wxt    = (u16*)(ws + 0);          // 512*256*2   = 262144
  u32* WhA    = (u32*)(ws + 262144);     // 512*64*4    = 131072
  float* c_ws = (float*)(ws + 393216);   // 256*128*4   = 131072
  u16* h_ws   = (u16*)(ws + 524288);     // 256*128*2   = 65536
  float* biasp= (float*)(ws + 589824);   // 512*4       = 2048
  u16* Xw     = (u16*)(ws + 591872);     // 256*CT*512*2

  // largest power-of-two T-chunk that fits the workspace (>=128 for gemm tiles)
  int CT = 512;
  while (CT > 128 && 591872 + (size_t)262144 * CT > ws_size) CT >>= 1;
  int ctl = __builtin_ctz((unsigned)CT);

  prep_kernel<<<642, 256, 0, stream>>>(Wx, Wh, bias, Wxt, WhA, biasp);
  for (int t0 = 0; t0 < T_; t0 += CT) {
    gemm_xw<<<dim3(4, 2 * CT), 256, 0, stream>>>(xs, Wxt, biasp, Xw, t0, ctl);
    lstm_mfma<<<16, 512, 0, stream>>>(Xw, WhA, c_ws, h_ws, t0, CT);
  }
  head_kernel<<<256, 128, 0, stream>>>(h_ws, W1, b1, W2, b2, out);
}

// Round 12
// 673.527 us; speedup vs baseline: 1.0744x; 1.0744x over previous
//
#include <hip/hip_runtime.h>
#include <hip/hip_fp16.h>

typedef unsigned short u16;
typedef unsigned int u32;

#define B_   256
#define T_   512
#define OBS_ 256
#define H_   128
#define G4_  512   // 4*H
#define LAT_ 16

typedef _Float16 half8_t __attribute__((ext_vector_type(8)));
typedef _Float16 half2_t __attribute__((ext_vector_type(2)));
typedef float    f32x4_t __attribute__((ext_vector_type(4)));

__device__ __forceinline__ u16 f2h(float x) { return __half_as_ushort(__float2half(x)); }
__device__ __forceinline__ float h2f(u16 u) { return __half2float(__ushort_as_half(u)); }
__device__ __forceinline__ float frcp(float x) { return __builtin_amdgcn_rcpf(x); }
__device__ __forceinline__ float fsigmoid(float x) { return frcp(1.f + __expf(-x)); }
__device__ __forceinline__ float ftanh(float x) { return 1.f - 2.f * frcp(1.f + __expf(2.f * x)); }

// ---------------------------------------------------------------------------
// Column permutations (baked into prep), R11 16-wave edition:
//  sigma(s): Xw/bias storage col s = w2*32 + kg*8 + ti*4 + q -> original col
//            q*128 + ((w2*2+ti)*4 + kg).   (thread (w2,kg) reads 8 contiguous
//            u16 per step covering its 2 tiles x 4 gates)
//  perm_g(g): WhA storage row g -> original gate col (g&3)*128 + (g>>2).
//            (D row g = tile*16 + kg*4 + r -> gate r of h-col tile*4+kg)
// ---------------------------------------------------------------------------
__device__ __forceinline__ int sigma_c(int s) {
  return (s & 3) * 128 + ((s >> 5) * 2 + ((s >> 2) & 1)) * 4 + ((s >> 3) & 3);
}
__device__ __forceinline__ int perm_g(int g) { return (g & 3) * 128 + (g >> 2); }

// ---------------------------------------------------------------------------
// prep: Wxt[s][k]  = f16(Wx[k][sigma(s)])                     (512 x 256)
//       WhA[g][k2] = pack(f16(Wh[2k2][perm_g(g)]), f16(Wh[2k2+1][perm_g(g)]))
//       biasp[s]   = bias[sigma(s)]
// ---------------------------------------------------------------------------
__global__ __launch_bounds__(256) void prep_kernel(const float* __restrict__ Wx,
                                                   const float* __restrict__ Wh,
                                                   const float* __restrict__ bias,
                                                   u16* __restrict__ Wxt,
                                                   u32* __restrict__ WhA,
                                                   float* __restrict__ biasp) {
  int idx = blockIdx.x * 256 + threadIdx.x;
  if (idx < G4_ * OBS_) {
    int s = idx / OBS_, k = idx % OBS_;
    Wxt[idx] = f2h(Wx[(size_t)k * G4_ + sigma_c(s)]);
  } else if (idx < G4_ * OBS_ + 64 * G4_) {
    int i2 = idx - G4_ * OBS_;
    int g = i2 >> 6, k2 = i2 & 63;
    int pg = perm_g(g);
    u32 lo = f2h(Wh[(size_t)(2 * k2) * G4_ + pg]);
    u32 hi = f2h(Wh[(size_t)(2 * k2 + 1) * G4_ + pg]);
    WhA[(size_t)g * 64 + k2] = lo | (hi << 16);
  } else if (idx < G4_ * OBS_ + 64 * G4_ + G4_) {
    int s = idx - G4_ * OBS_ - 64 * G4_;
    biasp[s] = bias[sigma_c(s)];
  }
}

// ---------------------------------------------------------------------------
// gemm_xw: Xw[m][s] = f16( sum_k xs_row(m)[k] * Wxt[s][k] + biasp[s] ).
// 128x128 tile, BK=64, 4 waves, 4x4 frags; C-init = bias.  (unchanged)
// ---------------------------------------------------------------------------
__global__ __launch_bounds__(256, 2) void gemm_xw(const float* __restrict__ xs,
                                                  const u16* __restrict__ Wxt,
                                                  const float* __restrict__ biasp,
                                                  u16* __restrict__ Xw,
                                                  int t0, int ct_log2) {
  __shared__ __align__(16) u16 As[128][88];
  __shared__ __align__(16) u16 Bs[128][88];

  const int tid  = threadIdx.x;
  const int lane = tid & 63;
  const int w    = tid >> 6;
  const int qr   = (w & 1) * 64;
  const int qc   = (w >> 1) * 64;
  const int bn   = blockIdx.x;
  const int bm   = blockIdx.y;

  f32x4_t acc[4][4];
#pragma unroll
  for (int ni = 0; ni < 4; ++ni) {
    float b = biasp[bn * 128 + qc + ni * 16 + (lane & 15)];
#pragma unroll
    for (int mi = 0; mi < 4; ++mi)
      acc[mi][ni] = (f32x4_t){b, b, b, b};
  }

  const int row  = tid >> 1;
  const int half = (tid & 1) * 32;
  const int m    = bm * 128 + row;
  const int bb   = m >> ct_log2;
  const int tau  = m & ((1 << ct_log2) - 1);
  const float* asrc = xs + (size_t)(bb * T_ + t0 + tau) * OBS_ + half;
  const u16*   bsrc = Wxt + (size_t)(bn * 128 + row) * OBS_ + half;

  for (int k0 = 0; k0 < OBS_; k0 += 64) {
    {
      const float* sp = asrc + k0;
#pragma unroll
      for (int i = 0; i < 4; ++i) {
        float4 v0 = *(const float4*)(sp + i * 8);
        float4 v1 = *(const float4*)(sp + i * 8 + 4);
        uint4 pk;
        pk.x = (u32)f2h(v0.x) | ((u32)f2h(v0.y) << 16);
        pk.y = (u32)f2h(v0.z) | ((u32)f2h(v0.w) << 16);
        pk.z = (u32)f2h(v1.x) | ((u32)f2h(v1.y) << 16);
        pk.w = (u32)f2h(v1.z) | ((u32)f2h(v1.w) << 16);
        *(uint4*)&As[row][half + i * 8] = pk;
      }
    }
    {
      const u16* sp = bsrc + k0;
#pragma unroll
      for (int i = 0; i < 4; ++i)
        *(uint4*)&Bs[row][half + i * 8] = *(const uint4*)(sp + i * 8);
    }
    __syncthreads();
#pragma unroll
    for (int ks = 0; ks < 2; ++ks) {
      const int kc = ks * 32 + (lane >> 4) * 8;
      half8_t af[4], bf[4];
#pragma unroll
      for (int mi = 0; mi < 4; ++mi) af[mi] = *(const half8_t*)&As[qr + mi * 16 + (lane & 15)][kc];
#pragma unroll
      for (int ni = 0; ni < 4; ++ni) bf[ni] = *(const half8_t*)&Bs[qc + ni * 16 + (lane & 15)][kc];
#pragma unroll
      for (int mi = 0; mi < 4; ++mi)
#pragma unroll
        for (int ni = 0; ni < 4; ++ni)
          acc[mi][ni] = __builtin_amdgcn_mfma_f32_16x16x32_f16(af[mi], bf[ni], acc[mi][ni], 0, 0, 0);
    }
    __syncthreads();
  }
#pragma unroll
  for (int mi = 0; mi < 4; ++mi)
#pragma unroll
    for (int ni = 0; ni < 4; ++ni)
#pragma unroll
      for (int r = 0; r < 4; ++r) {
        int mm = bm * 128 + qr + mi * 16 + (lane >> 4) * 4 + r;
        int nn = bn * 128 + qc + ni * 16 + (lane & 15);
        Xw[(size_t)mm * G4_ + nn] = f2h(acc[mi][ni][r]);
      }
}

// ---------------------------------------------------------------------------
// lstm_mfma (R11): 16 blocks x 1024 threads = 16 waves (4/SIMD).  R11 fix:
// R10's 8-wave version had ZERO pipe overlap (sum of pipe times == step time;
// all waves barrier-lockstepped in the same phase at 2 waves/SIMD).  16 waves
// x 2 tiles/wave halves per-wave work and doubles scheduler diversity so
// DS / MFMA / VALU / trans phases of different waves interleave.
// A = Wh pinned (32 VGPR, asm + immediate vmcnt(0)); B = h from LDS [row][k2]
// stride-72 (4 x ds_read_b128); Xw normal loads, 4-slot rotation.
// ---------------------------------------------------------------------------
#define HLS2 72   // u32 stride per batch row (16B-aligned)

__global__ __launch_bounds__(1024, 4)
void lstm_mfma(const u16* __restrict__ Xw,
               const u32* __restrict__ WhA,
               float* __restrict__ c_ws,
               u16* __restrict__ h_ws,
               int t0, int CT) {
  const int tid  = threadIdx.x;
  const int lane = tid & 63;
  const int w2   = tid >> 6;      // 0..15
  const int n    = lane & 15;     // batch row within the 16-row group
  const int kg   = lane >> 4;     // 0..3 (k-slice / j-subindex)
  const int b0   = blockIdx.x * 16;

  __shared__ u32 hl[2][16 * HLS2];

  // ---- A-fragments (Wh): asm loads, then settle IMMEDIATELY ----
  uint4 A[2][4];
#pragma unroll
  for (int ti = 0; ti < 2; ++ti) {
    const int mg = (w2 * 2 + ti) * 16 + n;
    const u32* ap = WhA + (size_t)mg * 64 + kg * 4;
#pragma unroll
    for (int kf = 0; kf < 4; ++kf)
      asm volatile("global_load_dwordx4 %0, %1, off" : "=v"(A[ti][kf]) : "v"(ap + kf * 16));
  }
  asm volatile("s_waitcnt vmcnt(0)" ::: "memory");
  __builtin_amdgcn_sched_barrier(0);

  // ---- state init ----
  float c_reg[2], h_last[2];
#pragma unroll
  for (int ti = 0; ti < 2; ++ti) { c_reg[ti] = 0.f; h_last[ti] = 0.f; }
  if (t0 != 0) {
#pragma unroll
    for (int ti = 0; ti < 2; ++ti)
      c_reg[ti] = c_ws[(size_t)(b0 + n) * 128 + (w2 * 2 + ti) * 4 + kg];
  }
  {
    const u32* hws32 = (const u32*)h_ws;
    int r = tid >> 6, k2 = tid & 63;    // 1024 threads cover 16x64 exactly
    hl[0][r * HLS2 + k2] = (t0 == 0) ? 0u : hws32[(size_t)(b0 + r) * 64 + k2];
  }
  __syncthreads();

  // ---- Xw base: this thread's 8 contiguous u16 per step (2 tiles x 4 gates) ----
  const u16* xrow = Xw + (size_t)((b0 + n) * CT) * 512 + w2 * 32 + kg * 8;

  auto step = [&](const uint4& xq, int cur) {
    const u32* hb = hl[cur];
    uint4 Bf[4];
#pragma unroll
    for (int kf = 0; kf < 4; ++kf)
      Bf[kf] = *(const uint4*)&hb[n * HLS2 + kf * 16 + kg * 4];
    u32 xv[4] = {xq.x, xq.y, xq.z, xq.w};
#pragma unroll
    for (int ti = 0; ti < 2; ++ti) {
      f32x4_t acc = (f32x4_t){0.f, 0.f, 0.f, 0.f};
#pragma unroll
      for (int kf = 0; kf < 4; ++kf)
        acc = __builtin_amdgcn_mfma_f32_16x16x32_f16(
            __builtin_bit_cast(half8_t, A[ti][kf]),
            __builtin_bit_cast(half8_t, Bf[kf]), acc, 0, 0, 0);
      half2_t xlo = __builtin_bit_cast(half2_t, xv[2 * ti]);       // gates i,f
      half2_t xhi = __builtin_bit_cast(half2_t, xv[2 * ti + 1]);   // gates g,o
      float ig = fsigmoid(acc[0] + (float)xlo[0]);
      float fg = fsigmoid(acc[1] + (float)xlo[1]);
      float gt = ftanh   (acc[2] + (float)xhi[0]);
      float og = fsigmoid(acc[3] + (float)xhi[1]);
      c_reg[ti] = fmaf(fg, c_reg[ti], ig * gt);
      float h = og * ftanh(c_reg[ti]);
      h_last[ti] = h;
      const int j = (w2 * 2 + ti) * 4 + kg;
      ((u16*)&hl[cur ^ 1][0])[(n * HLS2 + (j >> 1)) * 2 + (j & 1)] = f2h(h);
    }
    __syncthreads();
  };

  // ---- prologue: load xw for t = 0..3 (normal loads, compiler waitcnts) ----
  uint4 q0 = *(const uint4*)(xrow + 0 * 512);
  uint4 q1 = *(const uint4*)(xrow + 1 * 512);
  uint4 q2 = *(const uint4*)(xrow + 2 * 512);
  uint4 q3 = *(const uint4*)(xrow + 3 * 512);

  for (int base = 0; base < CT; base += 4) {
    int r0 = base + 4 < CT ? base + 4 : CT - 1;   // tail reloads are dead
    int r1 = base + 5 < CT ? base + 5 : CT - 1;
    int r2 = base + 6 < CT ? base + 6 : CT - 1;
    int r3 = base + 7 < CT ? base + 7 : CT - 1;
    step(q0, 0);
    q0 = *(const uint4*)(xrow + (size_t)r0 * 512);
    step(q1, 1);
    q1 = *(const uint4*)(xrow + (size_t)r1 * 512);
    step(q2, 0);
    q2 = *(const uint4*)(xrow + (size_t)r2 * 512);
    step(q3, 1);
    q3 = *(const uint4*)(xrow + (size_t)r3 * 512);
  }

#pragma unroll
  for (int ti = 0; ti < 2; ++ti) {
    const int j = (w2 * 2 + ti) * 4 + kg;
    c_ws[(size_t)(b0 + n) * 128 + j] = c_reg[ti];
    h_ws[(size_t)(b0 + n) * 128 + j] = f2h(h_last[ti]);
  }
}

// ---------------------------------------------------------------------------
// head: out1 = relu(h @ W1 + b1); p = out1 @ W2 + b2; split mean/logvar.
// ---------------------------------------------------------------------------
__global__ __launch_bounds__(128) void head_kernel(const u16* __restrict__ h_ws,
                                                   const float* __restrict__ W1,
                                                   const float* __restrict__ b1,
                                                   const float* __restrict__ W2,
                                                   const float* __restrict__ b2,
                                                   float* __restrict__ out) {
  const int bb = blockIdx.x;
  const int j  = threadIdx.x;
  __shared__ float hs[128];
  __shared__ float o1[128];
  hs[j] = h2f(h_ws[bb * 128 + j]);
  __syncthreads();
  float acc = b1[j];
#pragma unroll 8
  for (int k = 0; k < 128; ++k) acc = fmaf(hs[k], W1[(size_t)k * 128 + j], acc);
  o1[j] = fmaxf(acc, 0.f);
  __syncthreads();
  if (j < 2 * LAT_) {
    float acc2 = b2[j];
#pragma unroll 8
    for (int k = 0; k < 128; ++k) acc2 = fmaf(o1[k], W2[(size_t)k * (2 * LAT_) + j], acc2);
    if (j < LAT_) out[(size_t)bb * LAT_ + j] = acc2;                       // mean
    else          out[(size_t)B_ * LAT_ + (size_t)bb * LAT_ + (j - LAT_)] = acc2;  // logvar
  }
}

// ---------------------------------------------------------------------------
extern "C" void kernel_launch(void* const* d_in, const int* in_sizes, int n_in,
                              void* d_out, int out_size, void* d_ws, size_t ws_size,
                              hipStream_t stream) {
  const float* xs   = (const float*)d_in[0];
  const float* Wx   = (const float*)d_in[1];
  const float* Wh   = (const float*)d_in[2];
  const float* bias = (const float*)d_in[3];
  const float* W1   = (const float*)d_in[4];
  const float* b1   = (const float*)d_in[5];
  const float* W2   = (const float*)d_in[6];
  const float* b2   = (const float*)d_in[7];
  float* out = (float*)d_out;

  char* ws = (char*)d_ws;
  u16* Wxt    = (u16*)(ws + 0);          // 512*256*2   = 262144
  u32* WhA    = (u32*)(ws + 262144);     // 512*64*4    = 131072
  float* c_ws = (float*)(ws + 393216);   // 256*128*4   = 131072
  u16* h_ws   = (u16*)(ws + 524288);     // 256*128*2   = 65536
  float* biasp= (float*)(ws + 589824);   // 512*4       = 2048
  u16* Xw     = (u16*)(ws + 591872);     // 256*CT*512*2

  // largest power-of-two T-chunk that fits the workspace (>=128 for gemm tiles)
  int CT = 512;
  while (CT > 128 && 591872 + (size_t)262144 * CT > ws_size) CT >>= 1;
  int ctl = __builtin_ctz((unsigned)CT);

  prep_kernel<<<642, 256, 0, stream>>>(Wx, Wh, bias, Wxt, WhA, biasp);
  for (int t0 = 0; t0 < T_; t0 += CT) {
    gemm_xw<<<dim3(4, 2 * CT), 256, 0, stream>>>(xs, Wxt, biasp, Xw, t0, ctl);
    lstm_mfma<<<16, 1024, 0, stream>>>(Xw, WhA, c_ws, h_ws, t0, CT);
  }
  head_kernel<<<256, 128, 0, stream>>>(h_ws, W1, b1, W2, b2, out);
}